// Round 7
// baseline (72.749 us; speedup 1.0000x reference)
//
#include <hip/hip_runtime.h>

#define BB 4
#define MM 128
#define LL 512
#define DD 768
#define NEGF (-1e30f)

// Two-phase decomposition. Seven schedule/locality variants (r0-r6) all ran
// ~40us because per-CU cold bytes were invariant: every block read a full
// 393KB h-slice (m-reuse was cross-block). Per-CU service is capped (~56
// lines in flight @ ~375ns -> ~10GB/s/CU), so the fix is fewer bytes/CU:
// split L across blocks, reuse h in-block via LDS.
//   K1: block (b,dch,lch,mch-half) stages 64 rows x 192 floats in LDS once;
//       16 waves x 4 mentions each compute from LDS. Cold bytes/CU:
//       49KB h + 16KB mask = 65KB (6.3x less). Partials -> ws.
//   K2: 8-way max over lch partials -> out. Writer/reader XCD-matched
//       (flat%8 = grp) so partial reads hit that XCD's L2/L3.
// Bit-exact: max over a partition of L of (h + {0,-1e30}) then max of
// partials == reference; all-masked chunks give exactly -1e30.
// Fallback: if ws_size < 12.6MB, run the r6 monolithic kernel.

typedef __attribute__((address_space(1))) const unsigned int gu32_t;
typedef __attribute__((address_space(3))) unsigned int lu32_t;

#define PARTIAL_FLOATS (64 * 768)            // one (lch,grp) partial
#define WS_FLOATS (64 * PARTIAL_FLOATS)      // 8 lch x 8 grp
#define LCH_STRIDE (8 * PARTIAL_FLOATS)      // float stride between lch

// ---------------- Kernel 1: per-L-chunk partial max ----------------
__global__ __launch_bounds__(1024, 4) void mention_part_kernel(
    const float* __restrict__ h, const int* __restrict__ mask,
    float* __restrict__ ws)
{
    const int lane = threadIdx.x & 63;
    const int wave = threadIdx.x >> 6;   // 0..15

    const int flat = blockIdx.x;         // 0..255
    const int grp  = flat & 7;           // XCD id = b*2+mch
    const int b    = grp >> 1;
    const int mch  = grp & 1;
    const int inner = flat >> 3;         // 0..31
    const int dch  = inner >> 3;         // 0..3
    const int lch  = inner & 7;          // 0..7

    const int l0   = lch * 64;
    const int mloc0 = wave * 4;          // local mention base (0..60)

    __shared__ float hs[64 * 192];       // 49152 B

    // 1) mask loads first: wave's 4 mentions x 64 l (lane = l).
    const int* mp = mask +
        ((size_t)(b * MM + mch * 64 + mloc0)) * LL + l0 + lane;
    const int mv0 = mp[0 * LL];
    const int mv1 = mp[1 * LL];
    const int mv2 = mp[2 * LL];
    const int mv3 = mp[3 * LL];

    // 2) DMA half A (rows 0..31): wave stages rows 2w, 2w+1.
    const float* hrow = h + ((size_t)(b * LL + l0)) * DD + dch * 192;
#define STAGE_ROW(R) do {                                                     \
        const float* _s = hrow + (size_t)(R) * DD;                            \
        float* _d = hs + (R) * 192;                                           \
        __builtin_amdgcn_global_load_lds((gu32_t*)(_s + 0 * 64 + lane),       \
                                         (lu32_t*)(_d + 0 * 64), 4, 0, 0);    \
        __builtin_amdgcn_global_load_lds((gu32_t*)(_s + 1 * 64 + lane),       \
                                         (lu32_t*)(_d + 1 * 64), 4, 0, 0);    \
        __builtin_amdgcn_global_load_lds((gu32_t*)(_s + 2 * 64 + lane),       \
                                         (lu32_t*)(_d + 2 * 64), 4, 0, 0);    \
    } while (0)
    STAGE_ROW(2 * wave);
    STAGE_ROW(2 * wave + 1);

    // 3) ballots -> SGPR 64-bit masks (the wait is subsumed by barrier 1).
    unsigned blo[4], bhi[4];
    { unsigned long long bl = __ballot(mv0 != 0);
      blo[0] = __builtin_amdgcn_readfirstlane((unsigned)bl);
      bhi[0] = __builtin_amdgcn_readfirstlane((unsigned)(bl >> 32)); }
    { unsigned long long bl = __ballot(mv1 != 0);
      blo[1] = __builtin_amdgcn_readfirstlane((unsigned)bl);
      bhi[1] = __builtin_amdgcn_readfirstlane((unsigned)(bl >> 32)); }
    { unsigned long long bl = __ballot(mv2 != 0);
      blo[2] = __builtin_amdgcn_readfirstlane((unsigned)bl);
      bhi[2] = __builtin_amdgcn_readfirstlane((unsigned)(bl >> 32)); }
    { unsigned long long bl = __ballot(mv3 != 0);
      blo[3] = __builtin_amdgcn_readfirstlane((unsigned)bl);
      bhi[3] = __builtin_amdgcn_readfirstlane((unsigned)(bl >> 32)); }

    __syncthreads();     // barrier 1: half-A DMA drained (compiler vmcnt(0))

    // 4) DMA half B in flight while half A computes.
    STAGE_ROW(32 + 2 * wave);
    STAGE_ROW(33 + 2 * wave);
#undef STAGE_ROW

    float ax[4], ay[4], az[4];
#pragma unroll
    for (int q = 0; q < 4; ++q) { ax[q] = NEGF; ay[q] = NEGF; az[q] = NEGF; }

    // add-pair + max3 = 1.5 VALU/elem; ad from SGPR bits (SALU, ~free).
#define CHALF(BASE, W)                                                        \
    _Pragma("unroll")                                                         \
    for (int r = 0; r < 32; r += 2) {                                         \
        const float* rp0 = hs + (BASE + r) * 192;                             \
        const float* rp1 = rp0 + 192;                                         \
        const float x0 = rp0[lane], y0 = rp0[64 + lane], z0 = rp0[128 + lane];\
        const float x1 = rp1[lane], y1 = rp1[64 + lane], z1 = rp1[128 + lane];\
        _Pragma("unroll")                                                     \
        for (int q = 0; q < 4; ++q) {                                         \
            const float ad0 = ((W[q] >> r) & 1u) ? 0.0f : NEGF;               \
            const float ad1 = ((W[q] >> (r + 1)) & 1u) ? 0.0f : NEGF;         \
            ax[q] = fmaxf(fmaxf(x0 + ad0, x1 + ad1), ax[q]);                  \
            ay[q] = fmaxf(fmaxf(y0 + ad0, y1 + ad1), ay[q]);                  \
            az[q] = fmaxf(fmaxf(z0 + ad0, z1 + ad1), az[q]);                  \
        }                                                                     \
    }

    CHALF(0, blo)
    __syncthreads();     // barrier 2: half-B DMA drained
    CHALF(32, bhi)
#undef CHALF

    // 5) write partials: ws[lch*8+grp][mloc][d] (coalesced dwords).
    float* wp = ws + ((size_t)(lch * 8 + grp)) * PARTIAL_FLOATS
                   + (size_t)mloc0 * 768 + dch * 192;
#pragma unroll
    for (int q = 0; q < 4; ++q) {
        wp[q * 768 + lane]       = ax[q];
        wp[q * 768 + 64 + lane]  = ay[q];
        wp[q * 768 + 128 + lane] = az[q];
    }
}

// ---------------- Kernel 2: 8-way reduce of lch partials ----------------
__global__ __launch_bounds__(1024) void mention_reduce_kernel(
    const float* __restrict__ ws, float* __restrict__ out)
{
    const int flat = blockIdx.x;         // 0..255
    const int grp  = flat & 7;           // same XCD as the writers
    const int j    = flat >> 3;          // 0..31 -> 2 mentions each
    const int b    = grp >> 1;
    const int mch  = grp & 1;
    const int mloc = j * 2;

#pragma unroll
    for (int e0 = 0; e0 < 2; ++e0) {
        const int e = (int)threadIdx.x + e0 * 1024;   // 0..2047
        if (e < 1536) {
            const int m_ = e >> 9 >= 0 ? (e / 768) : 0;   // 0 or 1
            const int d  = e - m_ * 768;
            const float* p = ws + (size_t)grp * PARTIAL_FLOATS
                                + (size_t)(mloc + m_) * 768 + d;
            const float v0 = p[(size_t)0 * LCH_STRIDE];
            const float v1 = p[(size_t)1 * LCH_STRIDE];
            const float v2 = p[(size_t)2 * LCH_STRIDE];
            const float v3 = p[(size_t)3 * LCH_STRIDE];
            const float v4 = p[(size_t)4 * LCH_STRIDE];
            const float v5 = p[(size_t)5 * LCH_STRIDE];
            const float v6 = p[(size_t)6 * LCH_STRIDE];
            const float v7 = p[(size_t)7 * LCH_STRIDE];
            const float v = fmaxf(fmaxf(fmaxf(v0, v1), fmaxf(v2, v3)),
                                  fmaxf(fmaxf(v4, v5), fmaxf(v6, v7)));
            out[((size_t)(b * MM + mch * 64 + mloc + m_)) * DD + d] = v;
        }
    }
}

// ---------------- Fallback: r6 monolithic kernel (ws too small) ----------
__global__ __launch_bounds__(1024, 4) void mention_max_kernel(
    const float* __restrict__ h, const int* __restrict__ mask,
    float* __restrict__ out)
{
    const int lane = threadIdx.x & 63;
    const int wave = threadIdx.x >> 6;

    const int flat  = blockIdx.x;
    const int slice = flat & 15;
    const int mch   = flat >> 4;
    const int b     = slice >> 2;
    const int dch   = slice & 3;

    const int m0 = mch * 8;
    const int l0 = wave * 32;

    const int half = lane >> 5;
    const int lrow = lane & 31;
    const int* mp = mask + ((size_t)(b * MM + m0)) * LL + l0 + lrow;
    const int mv0 = mp[(0 + half) * LL];
    const int mv1 = mp[(2 + half) * LL];
    const int mv2 = mp[(4 + half) * LL];
    const int mv3 = mp[(6 + half) * LL];

    unsigned wbits[8];
    { unsigned long long bl = __ballot(mv0 != 0);
      wbits[0] = __builtin_amdgcn_readfirstlane((unsigned)bl);
      wbits[1] = __builtin_amdgcn_readfirstlane((unsigned)(bl >> 32)); }
    { unsigned long long bl = __ballot(mv1 != 0);
      wbits[2] = __builtin_amdgcn_readfirstlane((unsigned)bl);
      wbits[3] = __builtin_amdgcn_readfirstlane((unsigned)(bl >> 32)); }
    { unsigned long long bl = __ballot(mv2 != 0);
      wbits[4] = __builtin_amdgcn_readfirstlane((unsigned)bl);
      wbits[5] = __builtin_amdgcn_readfirstlane((unsigned)(bl >> 32)); }
    { unsigned long long bl = __ballot(mv3 != 0);
      wbits[6] = __builtin_amdgcn_readfirstlane((unsigned)bl);
      wbits[7] = __builtin_amdgcn_readfirstlane((unsigned)(bl >> 32)); }

    __builtin_amdgcn_sched_barrier(0);

    const float* glane = h + ((size_t)(b * LL + l0)) * DD + dch * 192 + lane;
    float sx[12], sy[12], sz[12];

#define ISSUE_ROW(ROW, S) do {                                                \
        const float* _a = glane + (size_t)(ROW) * DD;                         \
        asm volatile("global_load_dword %0, %1, off"                          \
                     : "=v"(sx[S]) : "v"(_a) : "memory");                     \
        asm volatile("global_load_dword %0, %1, off offset:256"               \
                     : "=v"(sy[S]) : "v"(_a) : "memory");                     \
        asm volatile("global_load_dword %0, %1, off offset:512"               \
                     : "=v"(sz[S]) : "v"(_a) : "memory");                     \
    } while (0)
#define WAITROW_(N, S)                                                        \
    asm volatile("s_waitcnt vmcnt(" #N ")"                                    \
                 : "+v"(sx[S]), "+v"(sy[S]), "+v"(sz[S]) :: "memory")
#define WAITROW(N, S) WAITROW_(N, S)

    float accx[8], accy[8], accz[8];
#pragma unroll
    for (int m = 0; m < 8; ++m) { accx[m] = NEGF; accy[m] = NEGF; accz[m] = NEGF; }

#define CONSUME(I, S) do {                                                    \
        const float vx = sx[S], vy = sy[S], vz = sz[S];                       \
        _Pragma("unroll")                                                     \
        for (int m = 0; m < 8; ++m) {                                         \
            if ((wbits[m] >> (I)) & 1u) {                                     \
                accx[m] = fmaxf(accx[m], vx);                                 \
                accy[m] = fmaxf(accy[m], vy);                                 \
                accz[m] = fmaxf(accz[m], vz);                                 \
            }                                                                 \
        }                                                                     \
    } while (0)

    ISSUE_ROW(0, 0);  ISSUE_ROW(1, 1);  ISSUE_ROW(2, 2);  ISSUE_ROW(3, 3);
    ISSUE_ROW(4, 4);  ISSUE_ROW(5, 5);  ISSUE_ROW(6, 6);  ISSUE_ROW(7, 7);
    ISSUE_ROW(8, 8);  ISSUE_ROW(9, 9);  ISSUE_ROW(10, 10); ISSUE_ROW(11, 11);

#define STEP(I, S) do { WAITROW(33, S); CONSUME(I, S); ISSUE_ROW((I) + 12, S); } while (0)
    STEP(0, 0);   STEP(1, 1);   STEP(2, 2);   STEP(3, 3);
    STEP(4, 4);   STEP(5, 5);   STEP(6, 6);   STEP(7, 7);
    STEP(8, 8);   STEP(9, 9);   STEP(10, 10); STEP(11, 11);
    STEP(12, 0);  STEP(13, 1);  STEP(14, 2);  STEP(15, 3);
    STEP(16, 4);  STEP(17, 5);  STEP(18, 6);  STEP(19, 7);
#undef STEP
#define DSTEP(I, S, N) do { WAITROW(N, S); CONSUME(I, S); } while (0)
    DSTEP(20, 8, 33);  DSTEP(21, 9, 30);  DSTEP(22, 10, 27); DSTEP(23, 11, 24);
    DSTEP(24, 0, 21);  DSTEP(25, 1, 18);  DSTEP(26, 2, 15);  DSTEP(27, 3, 12);
    DSTEP(28, 4, 9);   DSTEP(29, 5, 6);   DSTEP(30, 6, 3);   DSTEP(31, 7, 0);
#undef DSTEP
#undef CONSUME
#undef WAITROW
#undef WAITROW_
#undef ISSUE_ROW

    __shared__ float red[8][8][3][64];
    if (wave >= 8) {
#pragma unroll
        for (int m = 0; m < 8; ++m) {
            red[wave - 8][m][0][lane] = accx[m];
            red[wave - 8][m][1][lane] = accy[m];
            red[wave - 8][m][2][lane] = accz[m];
        }
    }
    __syncthreads();
    if (wave < 8) {
#pragma unroll
        for (int m = 0; m < 8; ++m) {
            red[wave][m][0][lane] = fmaxf(accx[m], red[wave][m][0][lane]);
            red[wave][m][1][lane] = fmaxf(accy[m], red[wave][m][1][lane]);
            red[wave][m][2][lane] = fmaxf(accz[m], red[wave][m][2][lane]);
        }
    }
    __syncthreads();

    if (threadIdx.x < 512) {
        const int m  = (int)(threadIdx.x >> 6);
        const int ln = (int)(threadIdx.x & 63);
        float vx = red[0][m][0][ln];
        float vy = red[0][m][1][ln];
        float vz = red[0][m][2][ln];
#pragma unroll
        for (int w = 1; w < 8; ++w) {
            vx = fmaxf(vx, red[w][m][0][ln]);
            vy = fmaxf(vy, red[w][m][1][ln]);
            vz = fmaxf(vz, red[w][m][2][ln]);
        }
        float* op = out + ((size_t)(b * MM + m0 + m)) * DD + dch * 192;
        op[ln]       = vx;
        op[64 + ln]  = vy;
        op[128 + ln] = vz;
    }
}

extern "C" void kernel_launch(void* const* d_in, const int* in_sizes, int n_in,
                              void* d_out, int out_size, void* d_ws, size_t ws_size,
                              hipStream_t stream) {
    const float* h    = (const float*)d_in[0];
    const int*   mask = (const int*)d_in[1];
    float*       out  = (float*)d_out;
    if (d_ws != nullptr && ws_size >= (size_t)WS_FLOATS * sizeof(float)) {
        float* ws = (float*)d_ws;
        mention_part_kernel<<<dim3(256), dim3(1024), 0, stream>>>(h, mask, ws);
        mention_reduce_kernel<<<dim3(256), dim3(1024), 0, stream>>>(ws, out);
    } else {
        mention_max_kernel<<<dim3(256), dim3(1024), 0, stream>>>(h, mask, out);
    }
}